// Round 7
// baseline (357.911 us; speedup 1.0000x reference)
//
#include <hip/hip_runtime.h>
#include <cstddef>

// Problem shape (fixed): N=50000, K=16, C_IN=128, C2=256, C_OUT=128.
#define C_IN  128
#define C2    256
#define C_OUT 128
#define KNBR  16
#define PTS   32     // points per gather_out block

typedef unsigned short u16;
typedef __attribute__((ext_vector_type(8))) short bf16x8;   // 8 bf16 (4 VGPRs)
typedef __attribute__((ext_vector_type(4))) float f32x4;

__device__ __forceinline__ float bf2f(u16 h) {
    return __uint_as_float(((unsigned int)h) << 16);
}
__device__ __forceinline__ u16 f2bf(float x) {
    unsigned int u = __float_as_uint(x);
    return (u16)((u + 0x7fffu + ((u >> 16) & 1u)) >> 16);
}

// Transpose + convert weights to bf16, n-major [N][K]; fold BN params.
__global__ void prep_k(const float* __restrict__ W1, const float* __restrict__ Ws,
                       const float* __restrict__ Wm, const float* __restrict__ b1,
                       const float* __restrict__ gamma, const float* __restrict__ beta,
                       const float* __restrict__ mean, const float* __restrict__ var,
                       u16* __restrict__ W1t, u16* __restrict__ Wst,
                       u16* __restrict__ Wmt, float4* __restrict__ bnp)
{
    const int n = blockIdx.x, t = threadIdx.x;
    if (blockIdx.y == 0) {
        if (t < 128) W1t[n * 128 + t] = f2bf(W1[t * 256 + n]);
    } else if (blockIdx.y == 1) {
        Wst[n * 256 + t] = f2bf(Ws[t * 256 + n]);
    } else if (blockIdx.y == 2) {
        if (n < 128) Wmt[n * 256 + t] = f2bf(Wm[t * 128 + n]);
    } else if (n == 0) {
        // x = (relu(z+b1)-mu)*iv + be = relu(z+c1)*c2 + c3
        float iv = gamma[t] * rsqrtf(var[t] + 1e-5f);
        bnp[t] = make_float4(b1[t], iv, beta[t] - mean[t] * iv, 0.f);
    }
}

// ---------------------------------------------------------------------------
// LESSONS ENCODED:
//  R7:  accumulator arrays indexed by non-unrolled loop vars spill to scratch.
//  R9:  scattered sub-dword global stores -> write-allocate RMW (watch 32B
//       segments: OK since each half-row is fully written by one wave).
//  R10: 1-block/CU weight-stationary waves have zero latency hiding — UNLESS
//       waves are barrier-free and independent (this round's structure).
//  R12: gather random-read fabric ~3.4 TB/s at full occupancy; FETCH ~370 MB
//       structural. SPLITTING THE GRID BELOW CAPACITY KILLS BW (R6: 2.85 at
//       1042 blocks, ~1.4 at 521). Single 1563-block dispatch only.
//  R14: launch_bounds cap below per-phase live state => silent scratch spill.
//  R15: interleaved (ey|x) packing proved WORTHLESS to gather (R1 null) ->
//       dropped; packed row = [ey 256 | x 256], both halves dense.
//  R17 (this round): mlp ~90 us vs ~10 us issue model across 3 structures ->
//       eliminate ALL structural couplings: weight-stationary LDS (padded,
//       2-way-bank-free), ONE barrier per kernel, waves fully independent,
//       grid-stride 16-row tiles. mlp1 writes x-half; mlp2 reads it (L3) as
//       A and writes ey-half. No Bs staging, no xs tile, no k-step barriers.
// ---------------------------------------------------------------------------

// mlp1: x = BN(relu(F @ W1 + b1)) -> packed x-half.
// W1t in LDS once, padded [256][136] (69.6 KB -> 2 blocks/CU, 8 waves/CU).
// Each wave owns 16 rows per tile; zero barriers in the loop.
__global__ __launch_bounds__(256)
void mlp1_k(const float* __restrict__ F, const u16* __restrict__ W1t,
            const float4* __restrict__ bnp, u16* __restrict__ packed, int N)
{
    __shared__ u16 Wl[256 * 136];   // 69.6 KB, stride 136 u16 (2-way banks)
    const int tid = threadIdx.x;
    const int w = tid >> 6, l = tid & 63, q = l >> 4, r = l & 15;

    // stage W1t once: 256 rows x 16 uint4 = 4096, 16/thread
    #pragma unroll
    for (int i = 0; i < 16; i++) {
        int idx = tid + i * 256;
        int row = idx >> 4, g = (idx & 15) * 8;
        *(uint4*)&Wl[row * 136 + g] = *(const uint4*)(W1t + row * 128 + g);
    }
    __syncthreads();   // the only barrier

    const int nwt = (N + 15) >> 4;          // 3125 wave-tiles
    const int nw = gridDim.x * 4;
    for (int wt = blockIdx.x * 4 + w; wt < nwt; wt += nw) {
        const int base = wt * 16;
        const int gr = min(base + r, N - 1);
        // A-frags: lane(q,r) = row base+r, k = kt*32 + q*8 .. +8
        bf16x8 af[4];
        #pragma unroll
        for (int kt = 0; kt < 4; kt++) {
            const float* s = F + (size_t)gr * C_IN + kt * 32 + q * 8;
            float4 v0 = *(const float4*)s;
            float4 v1 = *(const float4*)(s + 4);
            bf16x8 a;
            a[0] = (short)f2bf(v0.x); a[1] = (short)f2bf(v0.y);
            a[2] = (short)f2bf(v0.z); a[3] = (short)f2bf(v0.w);
            a[4] = (short)f2bf(v1.x); a[5] = (short)f2bf(v1.y);
            a[6] = (short)f2bf(v1.z); a[7] = (short)f2bf(v1.w);
            af[kt] = a;
        }
        #pragma unroll
        for (int j = 0; j < 16; j++) {
            f32x4 acc = {0.f, 0.f, 0.f, 0.f};
            #pragma unroll
            for (int kt = 0; kt < 4; kt++) {
                bf16x8 bf = *(const bf16x8*)&Wl[(j * 16 + r) * 136 + kt * 32 + q * 8];
                acc = __builtin_amdgcn_mfma_f32_16x16x32_bf16(af[kt], bf, acc, 0, 0, 0);
            }
            const float4 bp = bnp[j * 16 + r];      // col = j*16 + r
            #pragma unroll
            for (int p = 0; p < 4; p++) {
                const int gm = base + q * 4 + p;    // row = q*4 + p
                if (gm < N) {
                    float x = fmaxf(acc[p] + bp.x, 0.f) * bp.y + bp.z;
                    packed[(size_t)gm * 512 + 256 + j * 16 + r] = f2bf(x);
                }
            }
        }
    }
}

// mlp2: ey = exp(x @ Ws) -> packed ey-half. A = x-half (L3-resident).
// Wst in LDS once, padded [256][264] (132 KB -> 1 block/CU, but 8
// INDEPENDENT waves, zero barriers in the loop).
__global__ __launch_bounds__(512)
void mlp2_k(const u16* __restrict__ Wst, u16* __restrict__ packed, int N)
{
    __shared__ u16 Wsl[256 * 264];  // 132 KB, stride 264 u16 (2-way banks)
    const int tid = threadIdx.x;
    const int w = tid >> 6, l = tid & 63, q = l >> 4, r = l & 15;

    // stage Wst once: 256 rows x 32 uint4 = 8192, 16/thread
    #pragma unroll
    for (int i = 0; i < 16; i++) {
        int idx = tid + i * 512;
        int row = idx >> 5, g = (idx & 31) * 8;
        *(uint4*)&Wsl[row * 264 + g] = *(const uint4*)(Wst + row * 256 + g);
    }
    __syncthreads();   // the only barrier

    const int nwt = (N + 15) >> 4;          // 3125 wave-tiles
    const int nw = gridDim.x * 8;
    for (int wt = blockIdx.x * 8 + w; wt < nwt; wt += nw) {
        const int base = wt * 16;
        const int gr = min(base + r, N - 1);
        // A-frags from x-half: lane(q,r) = row base+r, k = kt*32 + q*8
        bf16x8 xa[8];
        #pragma unroll
        for (int kt = 0; kt < 8; kt++)
            xa[kt] = *(const bf16x8*)(packed + (size_t)gr * 512 + 256 + kt * 32 + q * 8);
        #pragma unroll
        for (int j = 0; j < 16; j++) {
            f32x4 acc = {0.f, 0.f, 0.f, 0.f};
            #pragma unroll
            for (int kt = 0; kt < 8; kt++) {
                bf16x8 bf = *(const bf16x8*)&Wsl[(j * 16 + r) * 264 + kt * 32 + q * 8];
                acc = __builtin_amdgcn_mfma_f32_16x16x32_bf16(xa[kt], bf, acc, 0, 0, 0);
            }
            #pragma unroll
            for (int p = 0; p < 4; p++) {
                const int gm = base + q * 4 + p;
                if (gm < N)
                    packed[(size_t)gm * 512 + j * 16 + r] = f2bf(__expf(acc[p]));
            }
        }
    }
}

// Fused gather + attentive pool + output GEMM. 32 points/block, 4 waves.
// Phase 1: each wave pools 8 points; 16 rows in TWO passes of 8 neighbors
//          (ey-half + x-half ushort4 loads, 32-VGPR payload -> no scratch).
// Phase 2: out[32 x 128] = feat @ Wmt + bm, B direct from L2-resident Wmt;
//          fp32 epilogue staging ALIASES the feat buffer.
// Single 1563-block dispatch (R12: never split below residency capacity).
__global__ __launch_bounds__(256, 5)
void gather_out_k(const u16* __restrict__ packed, const int* __restrict__ nidx,
                  const u16* __restrict__ Bt, const float* __restrict__ bias,
                  float* __restrict__ Cf, int N)
{
    __shared__ int rows[PTS * KNBR];                 // 2 KB
    __shared__ __align__(16) u16 fsm[PTS * 264];     // feat bf16 / STF fp32 alias

    const int tid = threadIdx.x;
    const int w = tid >> 6, l = tid & 63, q = l >> 4, r = l & 15;
    const int m0 = blockIdx.x * PTS;

    // stage neighbor indices: PTS*16 = 512 ints, 2/thread
    #pragma unroll
    for (int i = 0; i < 2; i++) {
        int idx = tid + i * 256;
        int n = m0 + (idx >> 4);
        rows[idx] = (n < N) ? nidx[n * KNBR + (idx & 15)] : 0;
    }
    __syncthreads();

    // ---- phase 1: gather + pool, wave w -> points w*8 .. w*8+7 ----
    #pragma unroll 1
    for (int ip = 0; ip < 8; ip++) {
        const int pl = w * 8 + ip;
        float num[4] = {0.f, 0.f, 0.f, 0.f};
        float den[4] = {0.f, 0.f, 0.f, 0.f};
        #pragma unroll 1
        for (int hf = 0; hf < 2; hf++) {
            ushort4 eh[8], xh[8];
            #pragma unroll
            for (int k = 0; k < 8; k++) {
                const size_t b = (size_t)rows[pl * KNBR + hf * 8 + k] * 512;
                eh[k] = *(const ushort4*)(packed + b + l * 4);
                xh[k] = *(const ushort4*)(packed + b + 256 + l * 4);
            }
            #pragma unroll
            for (int k = 0; k < 8; k++) {
                float e0 = bf2f(eh[k].x), e1 = bf2f(eh[k].y);
                float e2 = bf2f(eh[k].z), e3 = bf2f(eh[k].w);
                den[0] += e0; den[1] += e1; den[2] += e2; den[3] += e3;
                num[0] = fmaf(e0, bf2f(xh[k].x), num[0]);
                num[1] = fmaf(e1, bf2f(xh[k].y), num[1]);
                num[2] = fmaf(e2, bf2f(xh[k].z), num[2]);
                num[3] = fmaf(e3, bf2f(xh[k].w), num[3]);
            }
        }
        ushort4 o;
        o.x = f2bf(num[0] / den[0]); o.y = f2bf(num[1] / den[1]);
        o.z = f2bf(num[2] / den[2]); o.w = f2bf(num[3] / den[3]);
        *(ushort4*)&fsm[pl * 264 + l * 4] = o;   // rows >= N: garbage, never stored
    }
    __syncthreads();   // feat tile complete

    // ---- phase 2: out GEMM, wave grid 2M x 2N; B direct from L2 ----
    const int wm = w & 1, wn = w >> 1;
    f32x4 acc[4] = {};

    #pragma unroll
    for (int k0 = 0; k0 < C2; k0 += 64) {
        #pragma unroll
        for (int h = 0; h < 2; h++) {
            bf16x8 af, bfr[4];
            af = *(const bf16x8*)&fsm[(wm * 16 + r) * 264 + k0 + h * 32 + q * 8];
            #pragma unroll
            for (int j = 0; j < 4; j++)
                bfr[j] = *(const bf16x8*)(Bt +
                    (size_t)(wn * 64 + j * 16 + r) * C2 + k0 + h * 32 + q * 8);
            #pragma unroll
            for (int j = 0; j < 4; j++)
                acc[j] = __builtin_amdgcn_mfma_f32_16x16x32_bf16(
                    af, bfr[j], acc[j], 0, 0, 0);
        }
    }
    __syncthreads();   // all feat reads done -> safe to alias STF onto fsm

    // epilogue: stage fp32 tile in aliased LDS, then full-line float4 flush
    float* STF = (float*)fsm;              // [32][132]
    #pragma unroll
    for (int j = 0; j < 4; j++) {
        const int ch = wn * 64 + j * 16 + r;
        const float bo = bias[ch];
        const int mb = wm * 16 + q * 4;
        #pragma unroll
        for (int p = 0; p < 4; p++)
            STF[(mb + p) * 132 + ch] = acc[j][p] + bo;
    }
    __syncthreads();
    #pragma unroll
    for (int i = 0; i < 4; i++) {          // 32x128 fp32 = 1024 float4
        int idx = tid + i * 256;
        int row = idx >> 5, c4 = (idx & 31) * 4;
        if (m0 + row < N)
            *(float4*)(Cf + (size_t)(m0 + row) * C_OUT + c4) =
                *(const float4*)&STF[row * 132 + c4];
    }
}

extern "C" void kernel_launch(void* const* d_in, const int* in_sizes, int n_in,
                              void* d_out, int out_size, void* d_ws, size_t ws_size,
                              hipStream_t stream)
{
    const float* features = (const float*)d_in[0];
    const int*   nidx     = (const int*)d_in[1];
    const float* W1       = (const float*)d_in[2];
    const float* b1       = (const float*)d_in[3];
    const float* gamma    = (const float*)d_in[4];
    const float* beta     = (const float*)d_in[5];
    const float* mean     = (const float*)d_in[6];
    const float* var      = (const float*)d_in[7];
    const float* Ws       = (const float*)d_in[8];
    const float* Wm       = (const float*)d_in[9];
    const float* bm       = (const float*)d_in[10];
    float* out = (float*)d_out;

    const int N = in_sizes[0] / C_IN;   // 50000

    u16* packed = (u16*)d_ws;                      // N x 512: [ey 256 | x 256]
    u16* W1t    = packed + (size_t)N * 512;        // 256 x 128
    u16* Wst    = W1t + 256 * 128;                 // 256 x 256
    u16* Wmt    = Wst + 256 * 256;                 // 128 x 256
    float4* bnp = (float4*)(Wmt + 128 * 256);      // 256 folded BN params

    prep_k<<<dim3(256, 4), 256, 0, stream>>>(W1, Ws, Wm, b1, gamma, beta,
                                             mean, var, W1t, Wst, Wmt, bnp);

    const int GT = (N + PTS - 1) / PTS;  // 1563

    mlp1_k<<<512, 256, 0, stream>>>(features, W1t, bnp, packed, N);
    mlp2_k<<<256, 512, 0, stream>>>(Wst, packed, N);
    gather_out_k<<<GT, 256, 0, stream>>>(packed, nidx, Wmt, bm, out, N);
}